// Round 23
// baseline (298.132 us; speedup 1.0000x reference)
//
#include <hip/hip_runtime.h>
#include <hip/hip_bf16.h>

#define N_NODES 50000
#define N_EDGES 800000
#define F_IN 1024
#define F_MID 256
#define CSR_STRIDE 64    // bucketed CSR: max degree ~45 for Poisson(16); overflow-guarded

typedef _Float16 f16;
typedef _Float16 f16x4 __attribute__((ext_vector_type(4)));
typedef _Float16 f16x8 __attribute__((ext_vector_type(8)));
typedef float f32x4 __attribute__((ext_vector_type(4)));

// async global->LDS, 16B per lane. lds base wave-uniform; global addr per-lane.
__device__ __forceinline__ void glds16(const f16* g, f16* l) {
    __builtin_amdgcn_global_load_lds(
        (const __attribute__((address_space(1))) unsigned int*)g,
        (__attribute__((address_space(3))) unsigned int*)l, 16, 0, 0);
}

// ---------------- threefry2x32 (JAX-exact, key=(0,42)); verified: bits = x0^x1, ctr=(0,f) ----------------
__device__ __forceinline__ void tf_round(unsigned &x0, unsigned &x1, int r) {
    x0 += x1;
    x1 = (x1 << r) | (x1 >> (32 - r));
    x1 ^= x0;
}

__device__ __forceinline__ int keep_mask(unsigned f) {
    const unsigned ks0 = 0u, ks1 = 42u;
    const unsigned ks2 = ks0 ^ ks1 ^ 0x1BD11BDAu;
    unsigned x0 = 0u + ks0;
    unsigned x1 = f + ks1;
    tf_round(x0,x1,13); tf_round(x0,x1,15); tf_round(x0,x1,26); tf_round(x0,x1,6);
    x0 += ks1; x1 += ks2 + 1u;
    tf_round(x0,x1,17); tf_round(x0,x1,29); tf_round(x0,x1,16); tf_round(x0,x1,24);
    x0 += ks2; x1 += ks0 + 2u;
    tf_round(x0,x1,13); tf_round(x0,x1,15); tf_round(x0,x1,26); tf_round(x0,x1,6);
    x0 += ks0; x1 += ks1 + 3u;
    tf_round(x0,x1,17); tf_round(x0,x1,29); tf_round(x0,x1,16); tf_round(x0,x1,24);
    x0 += ks1; x1 += ks2 + 4u;
    tf_round(x0,x1,13); tf_round(x0,x1,15); tf_round(x0,x1,26); tf_round(x0,x1,6);
    x0 += ks2; x1 += ks0 + 5u;
    return (((x0 ^ x1) >> 31) == 0u);
}

__device__ __forceinline__ int ld_src(const int* ei, int e, int is64) {
    return is64 ? ei[2 * e] : ei[e];
}
__device__ __forceinline__ int ld_dst(const int* ei, int e, int is64) {
    return is64 ? ei[2 * N_EDGES + 2 * e] : ei[N_EDGES + e];
}

// ---------------- prep: zero cursor, dtype-detect, cvt+transpose+swizzle W1 ----------------
__global__ __launch_bounds__(256) void k_prep(const float* __restrict__ W1, f16* __restrict__ W1T,
                                              const int* __restrict__ ei,
                                              int* cursor, int* flag) {
    const int tid = threadIdx.x;
    const int gid = blockIdx.x * 256 + tid;
    const int gstr = gridDim.x * 256;
    if (gid < N_NODES) cursor[gid] = 0;
    if (blockIdx.x == 0) {
        if (tid == 0) flag[0] = 1;            // 1 = int64
        __syncthreads();
        int nz = 0;
        for (int k = tid; k < 1024; k += 256) nz |= (ei[2 * k + 1] != 0);
        if (nz) atomicAnd(flag, 0);
    }
    for (int i = gid; i < F_IN * F_MID; i += gstr) {
        int k = i >> 8, n = i & 255;          // W1 [1024][256]
        W1T[(size_t)n * F_IN + (k ^ ((n & 7) << 3))] = (f16)W1[i];
    }
}

// ---------------- MFMA f16 GEMM, BK=64, double-buffered, glds staging, swizzled LDS ----------------
// C[M,Ntot] = A[M,K] @ BT[Ntot,K]^T.  BT pre-swizzled ((k^((n&7)<<3)) in 64-half rows).
// M2: M-tiles per block (persistent; fewer scheduling rounds + amortized prologue).
// A16: A f16 pre-swizzled (glds); else f32 reg-staged (NT loads) + cvt + swizzled ds_write.
// Epilogue: acc -> LDS tile (stride BN+8) -> contiguous vector stores.
// C16: f16 out unscaled; else f32 + bias, nontemporal.
// Riders (>= mainx, GEMM1 only): bucketed-CSR fill (cursor = degree) + W2 cvt+transpose+swizzle.
template<int BM, int BN, int TN, int M2, bool A16, bool C16>
__global__ __launch_bounds__(TN) void k_mfma(const void* __restrict__ Ag,
                                             const f16* __restrict__ BTg,
                                             void* __restrict__ Cg,
                                             const float* __restrict__ bias,
                                             int M, int Ntot, int K, int mainx,
                                             const int* __restrict__ ei,
                                             int* __restrict__ cursor, int* __restrict__ csr,
                                             const int* __restrict__ flag,
                                             const float* __restrict__ Wr, f16* __restrict__ WrT) {
    if ((int)blockIdx.x >= mainx) {
        const int str = (gridDim.x - mainx) * TN;
        const int t0 = (blockIdx.x - mainx) * TN + threadIdx.x;
        const int is64 = flag[0];
        for (int e = t0; e < N_EDGES; e += str) {
            int d = ld_dst(ei, e, is64);
            int pos = atomicAdd(&cursor[d], 1);
            if (pos < CSR_STRIDE) csr[(size_t)d * CSR_STRIDE + pos] = ld_src(ei, e, is64);
        }
        for (int i = t0; i < F_MID * F_IN; i += str) {
            int k = i >> 10, n = i & 1023;    // Wr [256][1024]
            WrT[(size_t)n * F_MID + (k ^ ((n & 7) << 3))] = (f16)Wr[i];
        }
        return;
    }

    constexpr int BK = 64;
    constexpr int NW = TN / 64;
    constexpr int WM = BM / 64;
    constexpr int WN = NW / WM;
    constexpr int WTN = BN / WN;
    constexpr int FN = WTN / 16;
    constexpr int SMEM_STG = (2 * BM * BK + 2 * BN * BK) * 2;
    constexpr int LDC = BN + 8;
    constexpr int SMEM_EPI = BM * LDC * (C16 ? 2 : 4);
    constexpr int SMEM_SZ = SMEM_STG > SMEM_EPI ? SMEM_STG : SMEM_EPI;
    __shared__ __align__(16) char smem[SMEM_SZ];
    f16* As_ = (f16*)smem;                 // [2][BM*BK]
    f16* Bs_ = As_ + 2 * BM * BK;          // [2][BN*BK]

    const int tid = threadIdx.x, lane = tid & 63, wid = tid >> 6;
    const int l15 = lane & 15;
    const int wm = wid % WM, wn = wid / WM;
    const int col0 = blockIdx.y * BN;
    int row0 = blockIdx.x * (BM * M2);

    const int ar = tid >> 3;              // f32 A reg-staging (TN == BM*8)
    const int ac = (tid & 7) * 8;
    f32x4 av0 = {}, av1 = {};

    const int nkt = K / BK;

    auto stage_load = [&](int kt, int b) {
        const int k0 = kt * BK;
        if constexpr (A16) {
            const f16* A = (const f16*)Ag;
            #pragma unroll
            for (int i = wid; i < BM * BK / 512; i += NW) {
                int li = i * 512 + lane * 8;
                int r = li >> 6, c = li & 63;
                glds16(&A[(size_t)(row0 + r) * K + k0 + c], &As_[b * BM * BK + i * 512]);
            }
        } else {
            const float* A = (const float*)Ag;
            int gr = row0 + ar;
            if (gr < M) {
                av0 = __builtin_nontemporal_load((const f32x4*)&A[(size_t)gr * K + k0 + ac]);
                av1 = __builtin_nontemporal_load((const f32x4*)&A[(size_t)gr * K + k0 + ac + 4]);
            } else { av0 = (f32x4){}; av1 = (f32x4){}; }
        }
        #pragma unroll
        for (int i = wid; i < BN * BK / 512; i += NW) {
            int li = i * 512 + lane * 8;
            int r = li >> 6, c = li & 63;
            glds16(&BTg[(size_t)(col0 + r) * K + k0 + c], &Bs_[b * BN * BK + i * 512]);
        }
    };
    auto stage_write = [&](int b) {
        if constexpr (!A16) {
            f16x4 l = __builtin_convertvector(av0, f16x4);
            f16x4 h = __builtin_convertvector(av1, f16x4);
            f16x8 v = { l[0], l[1], l[2], l[3], h[0], h[1], h[2], h[3] };
            *(f16x8*)&As_[b * BM * BK + ar * 64 + (ac ^ ((ar & 7) << 3))] = v;
        }
    };

    #pragma unroll
    for (int m2 = 0; m2 < M2; ++m2) {
        row0 = blockIdx.x * (BM * M2) + m2 * BM;
        if (row0 >= M) break;

        f32x4 acc[4][FN] = {};
        int buf = 0;

        stage_load(0, 0);
        stage_write(0);
        __syncthreads();

        for (int kt = 0; kt < nkt; ++kt) {
            if (kt + 1 < nkt) stage_load(kt + 1, buf ^ 1);
            #pragma unroll
            for (int ks = 0; ks < 2; ++ks) {
                const int cc = ks * 32 + (lane >> 4) * 8;
                f16x8 af[4], bf[FN];
                #pragma unroll
                for (int m = 0; m < 4; ++m) {
                    int r = wm * 64 + m * 16 + l15;
                    af[m] = *(const f16x8*)&As_[buf * BM * BK + r * 64 + (cc ^ ((r & 7) << 3))];
                }
                #pragma unroll
                for (int n = 0; n < FN; ++n) {
                    int r = wn * WTN + n * 16 + l15;
                    bf[n] = *(const f16x8*)&Bs_[buf * BN * BK + r * 64 + (cc ^ ((r & 7) << 3))];
                }
                #pragma unroll
                for (int m = 0; m < 4; ++m)
                    #pragma unroll
                    for (int n = 0; n < FN; ++n)
                        acc[m][n] = __builtin_amdgcn_mfma_f32_16x16x32_f16(af[m], bf[n], acc[m][n], 0, 0, 0);
            }
            if (kt + 1 < nkt) stage_write(buf ^ 1);
            __syncthreads();
            buf ^= 1;
        }

        // ---- epilogue: acc -> LDS (stride LDC) -> contiguous vector stores ----
        // C/D frag mapping: col=lane&15, row=(lane>>4)*4+reg
        if constexpr (C16) {
            f16* CT = (f16*)smem;
            #pragma unroll
            for (int m = 0; m < 4; ++m)
                #pragma unroll
                for (int j = 0; j < 4; ++j) {
                    const int rl = wm * 64 + m * 16 + (lane >> 4) * 4 + j;
                    #pragma unroll
                    for (int n = 0; n < FN; ++n)
                        CT[rl * LDC + wn * WTN + n * 16 + l15] = (f16)acc[m][n][j];
                }
            __syncthreads();
            f16* C = (f16*)Cg;
            constexpr int NCH = BM * BN / 8;
            #pragma unroll
            for (int ci = tid; ci < NCH; ci += TN) {
                const int r = ci / (BN / 8), c = (ci % (BN / 8)) * 8;
                const int gr = row0 + r;
                if (gr < M) {
                    f16x8 v = *(const f16x8*)&CT[r * LDC + c];
                    *(f16x8*)&C[(size_t)gr * Ntot + col0 + c] = v;
                }
            }
        } else {
            float* CT = (float*)smem;
            #pragma unroll
            for (int m = 0; m < 4; ++m)
                #pragma unroll
                for (int j = 0; j < 4; ++j) {
                    const int rl = wm * 64 + m * 16 + (lane >> 4) * 4 + j;
                    #pragma unroll
                    for (int n = 0; n < FN; ++n)
                        CT[rl * LDC + wn * WTN + n * 16 + l15] = acc[m][n][j];
                }
            __syncthreads();
            float* C = (float*)Cg;
            constexpr int NCH = BM * BN / 4;
            #pragma unroll
            for (int ci = tid; ci < NCH; ci += TN) {
                const int r = ci / (BN / 4), c = (ci % (BN / 4)) * 4;
                const int gr = row0 + r;
                if (gr < M) {
                    f32x4 v = *(const f32x4*)&CT[r * LDC + c];
                    v += *(const f32x4*)&bias[col0 + c];
                    __builtin_nontemporal_store(v, (f32x4*)&C[(size_t)gr * Ntot + col0 + c]);
                }
            }
        }
        if (m2 + 1 < M2) __syncthreads();   // all CT reads done before next tile's staging
    }
}

// ---------------- aggregation (wave per row, unroll-4 gather, bucketed CSR, inline rsqrt) ----------------
// cnt = cursor[row] (edge count), dinv(i) = rsqrtf(cnt_i + 1) computed inline.
// SCALED_IN=1: rows carry dinv[src] -> acc = hin[row] + sum hin[s]
// SCALED_IN=0: unscaled             -> acc = di*hin[row] + sum rsqrt(deg_s+1)*hin[s]
// Then *= di.  POST: +b1, relu, dropout, *di.  SWZ: write col ^ ((row&7)<<3).
template<int POST, int SWZ, int SCALED_IN>
__global__ __launch_bounds__(256) void k_agg16(const f16* __restrict__ hin,
                                               f16* __restrict__ hout,
                                               const int* __restrict__ csr,
                                               const int* __restrict__ cnt_arr,
                                               const float* __restrict__ bias) {
    const int wid = threadIdx.x >> 6;
    const int lane = threadIdx.x & 63;
    const int row = blockIdx.x * 4 + wid;
    const int cnt = cnt_arr[row];
    const int ch = lane * 4;
    const float di = rsqrtf((float)(cnt + 1));
    const int* rowcsr = csr + (size_t)row * CSR_STRIDE;

    f32x4 acc = __builtin_convertvector(*(const f16x4*)&hin[(size_t)row * F_MID + ch], f32x4);
    if (!SCALED_IN) acc *= di;
    int k = 0;
    for (; k + 4 <= cnt; k += 4) {
        const int s0 = rowcsr[k], s1 = rowcsr[k + 1];
        const int s2 = rowcsr[k + 2], s3 = rowcsr[k + 3];
        f16x4 v0 = *(const f16x4*)&hin[(size_t)s0 * F_MID + ch];
        f16x4 v1 = *(const f16x4*)&hin[(size_t)s1 * F_MID + ch];
        f16x4 v2 = *(const f16x4*)&hin[(size_t)s2 * F_MID + ch];
        f16x4 v3 = *(const f16x4*)&hin[(size_t)s3 * F_MID + ch];
        if (SCALED_IN) {
            acc += __builtin_convertvector(v0, f32x4) + __builtin_convertvector(v1, f32x4)
                 + __builtin_convertvector(v2, f32x4) + __builtin_convertvector(v3, f32x4);
        } else {
            acc += rsqrtf((float)(cnt_arr[s0] + 1)) * __builtin_convertvector(v0, f32x4)
                 + rsqrtf((float)(cnt_arr[s1] + 1)) * __builtin_convertvector(v1, f32x4)
                 + rsqrtf((float)(cnt_arr[s2] + 1)) * __builtin_convertvector(v2, f32x4)
                 + rsqrtf((float)(cnt_arr[s3] + 1)) * __builtin_convertvector(v3, f32x4);
        }
    }
    for (; k < cnt; ++k) {
        const int s = rowcsr[k];
        f32x4 v = __builtin_convertvector(*(const f16x4*)&hin[(size_t)s * F_MID + ch], f32x4);
        acc += SCALED_IN ? v : rsqrtf((float)(cnt_arr[s] + 1)) * v;
    }
    acc *= di;

    if (POST) {
        const unsigned f0 = (unsigned)row * F_MID + (unsigned)ch;
        #pragma unroll
        for (int j = 0; j < 4; ++j) {
            float t = acc[j] + bias[ch + j];
            t = fmaxf(t, 0.0f);
            t = keep_mask(f0 + j) ? t * 2.0f : 0.0f;
            acc[j] = t * di;                 // pre-scale for next aggregation
        }
    }
    const int oc = SWZ ? (ch ^ ((row & 7) << 3)) : ch;
    *(f16x4*)&hout[(size_t)row * F_MID + oc] = __builtin_convertvector(acc, f16x4);
}

// ---------------- launch ----------------
extern "C" void kernel_launch(void* const* d_in, const int* in_sizes, int n_in,
                              void* d_out, int out_size, void* d_ws, size_t ws_size,
                              hipStream_t stream) {
    const float* x  = (const float*)d_in[0];
    const int*   ei = (const int*)d_in[1];
    const float* W1 = (const float*)d_in[2];
    const float* b1 = (const float*)d_in[3];
    const float* W2 = (const float*)d_in[4];
    const float* b2 = (const float*)d_in[5];
    float* out = (float*)d_out;

    // d_out doubles as fp16 scratch (dead before the final f32 overwrite):
    f16* h0 = (f16*)out;                               // [N,256] xW1, unscaled, linear
    f16* h1s = h0 + (size_t)N_NODES * F_MID;           // [N,256] post relu/dropout, dinv-scaled, linear

    // workspace (~40 MB)
    f16*   h2agg = (f16*)d_ws;                         // [N,256] agg2 out, row-swizzled (GEMM2 A)
    f16*   W1T   = h2agg + (size_t)(N_NODES + 64) * F_MID;  // [256][1024] swizzled (+pad: OOB-safe glds)
    f16*   W2T   = W1T + (size_t)F_MID * F_IN;         // [1024][256] swizzled
    int*   cursor= (int*)(W2T + (size_t)F_IN * F_MID); // [N] fill cursor == edge count (degree)
    int*   csr   = cursor + N_NODES;                   // [N*64] bucketed CSR
    int*   flag  = csr + (size_t)N_NODES * CSR_STRIDE; // [1] 1=int64, 0=int32

    // 1) prep: zero cursor, dtype detect, W1 -> W1T (swizzled)
    k_prep<<<256, 256, 0, stream>>>(W1, W1T, ei, cursor, flag);

    // 2) GEMM1 (+riders: bucketed-CSR fill, W2 -> W2T): h0 = x @ W1
    //    M2=2 persistent tiles -> mainx=391, +121 riders = 512 blocks = ONE scheduling round.
    {
        const int mainx = (N_NODES + 127) / 128;       // 391
        dim3 grid(mainx + 121, 1);                     // 512 exactly
        k_mfma<64, 256, 512, 2, false, true><<<grid, 512, 0, stream>>>(
            (const void*)x, W1T, (void*)h0, nullptr, N_NODES, F_MID, F_IN,
            mainx, ei, cursor, csr, flag, W2, W2T);
    }

    // 3) agg1: rsqrt-weighted gather; +b1, relu, dropout, pre-scale.  4) agg2: swizzled out.
    k_agg16<1, 0, 0><<<N_NODES / 4, 256, 0, stream>>>(h0, h1s, csr, cursor, b1);
    k_agg16<0, 1, 1><<<N_NODES / 4, 256, 0, stream>>>(h1s, h2agg, csr, cursor, nullptr);

    // 5) GEMM2: out = h2agg @ W2 + b2.  M2=2 persistent -> grid (391,4) = 1564 blocks (3 rounds).
    {
        const int mainx = (N_NODES + 127) / 128;       // 391
        dim3 grid(mainx, 4);
        k_mfma<64, 256, 512, 2, true, false><<<grid, 512, 0, stream>>>(
            (const void*)h2agg, W2T, (void*)out, b2, N_NODES, F_IN, F_MID,
            mainx, ei, cursor, csr, flag, W2, W2T);
    }
}

// Round 24
// 296.992 us; speedup vs baseline: 1.0038x; 1.0038x over previous
//
#include <hip/hip_runtime.h>
#include <hip/hip_bf16.h>

#define N_NODES 50000
#define N_EDGES 800000
#define F_IN 1024
#define F_MID 256
#define CSR_STRIDE 64    // bucketed CSR: max degree ~45 for Poisson(16); overflow-guarded

typedef _Float16 f16;
typedef _Float16 f16x4 __attribute__((ext_vector_type(4)));
typedef _Float16 f16x8 __attribute__((ext_vector_type(8)));
typedef float f32x4 __attribute__((ext_vector_type(4)));

// async global->LDS, 16B per lane. lds base wave-uniform; global addr per-lane.
__device__ __forceinline__ void glds16(const f16* g, f16* l) {
    __builtin_amdgcn_global_load_lds(
        (const __attribute__((address_space(1))) unsigned int*)g,
        (__attribute__((address_space(3))) unsigned int*)l, 16, 0, 0);
}

// ---------------- threefry2x32 (JAX-exact, key=(0,42)); verified: bits = x0^x1, ctr=(0,f) ----------------
__device__ __forceinline__ void tf_round(unsigned &x0, unsigned &x1, int r) {
    x0 += x1;
    x1 = (x1 << r) | (x1 >> (32 - r));
    x1 ^= x0;
}

__device__ __forceinline__ int keep_mask(unsigned f) {
    const unsigned ks0 = 0u, ks1 = 42u;
    const unsigned ks2 = ks0 ^ ks1 ^ 0x1BD11BDAu;
    unsigned x0 = 0u + ks0;
    unsigned x1 = f + ks1;
    tf_round(x0,x1,13); tf_round(x0,x1,15); tf_round(x0,x1,26); tf_round(x0,x1,6);
    x0 += ks1; x1 += ks2 + 1u;
    tf_round(x0,x1,17); tf_round(x0,x1,29); tf_round(x0,x1,16); tf_round(x0,x1,24);
    x0 += ks2; x1 += ks0 + 2u;
    tf_round(x0,x1,13); tf_round(x0,x1,15); tf_round(x0,x1,26); tf_round(x0,x1,6);
    x0 += ks0; x1 += ks1 + 3u;
    tf_round(x0,x1,17); tf_round(x0,x1,29); tf_round(x0,x1,16); tf_round(x0,x1,24);
    x0 += ks1; x1 += ks2 + 4u;
    tf_round(x0,x1,13); tf_round(x0,x1,15); tf_round(x0,x1,26); tf_round(x0,x1,6);
    x0 += ks2; x1 += ks0 + 5u;
    return (((x0 ^ x1) >> 31) == 0u);
}

__device__ __forceinline__ int ld_src(const int* ei, int e, int is64) {
    return is64 ? ei[2 * e] : ei[e];
}
__device__ __forceinline__ int ld_dst(const int* ei, int e, int is64) {
    return is64 ? ei[2 * N_EDGES + 2 * e] : ei[N_EDGES + e];
}

// ---------------- prep: zero cursor, dtype-detect, cvt+transpose+swizzle W1 ----------------
__global__ __launch_bounds__(256) void k_prep(const float* __restrict__ W1, f16* __restrict__ W1T,
                                              const int* __restrict__ ei,
                                              int* cursor, int* flag) {
    const int tid = threadIdx.x;
    const int gid = blockIdx.x * 256 + tid;
    const int gstr = gridDim.x * 256;
    if (gid < N_NODES) cursor[gid] = 0;
    if (blockIdx.x == 0) {
        if (tid == 0) flag[0] = 1;            // 1 = int64
        __syncthreads();
        int nz = 0;
        for (int k = tid; k < 1024; k += 256) nz |= (ei[2 * k + 1] != 0);
        if (nz) atomicAnd(flag, 0);
    }
    for (int i = gid; i < F_IN * F_MID; i += gstr) {
        int k = i >> 8, n = i & 255;          // W1 [1024][256]
        W1T[(size_t)n * F_IN + (k ^ ((n & 7) << 3))] = (f16)W1[i];
    }
}

// ---------------- MFMA f16 GEMM, BK=64, double-buffered, glds staging, swizzled LDS ----------------
// C[M,Ntot] = A[M,K] @ BT[Ntot,K]^T.  BT pre-swizzled ((k^((n&7)<<3)) in 64-half rows).
// M2: M-tiles per block (persistent; GEMM1 uses 2 -> grid fits one scheduling round).
// A16: A f16 pre-swizzled (glds); else f32 reg-staged (NT loads) + cvt + swizzled ds_write.
// Epilogue: acc -> LDS tile (stride BN+8) -> contiguous vector stores.
// C16: f16 out unscaled; else f32 + bias, nontemporal.
// Riders (>= mainx, GEMM1 only): bucketed-CSR fill (cursor = degree) + W2 cvt+transpose+swizzle.
template<int BM, int BN, int TN, int M2, bool A16, bool C16>
__global__ __launch_bounds__(TN) void k_mfma(const void* __restrict__ Ag,
                                             const f16* __restrict__ BTg,
                                             void* __restrict__ Cg,
                                             const float* __restrict__ bias,
                                             int M, int Ntot, int K, int mainx,
                                             const int* __restrict__ ei,
                                             int* __restrict__ cursor, int* __restrict__ csr,
                                             const int* __restrict__ flag,
                                             const float* __restrict__ Wr, f16* __restrict__ WrT) {
    if ((int)blockIdx.x >= mainx) {
        const int str = (gridDim.x - mainx) * TN;
        const int t0 = (blockIdx.x - mainx) * TN + threadIdx.x;
        const int is64 = flag[0];
        for (int e = t0; e < N_EDGES; e += str) {
            int d = ld_dst(ei, e, is64);
            int pos = atomicAdd(&cursor[d], 1);
            if (pos < CSR_STRIDE) csr[(size_t)d * CSR_STRIDE + pos] = ld_src(ei, e, is64);
        }
        for (int i = t0; i < F_MID * F_IN; i += str) {
            int k = i >> 10, n = i & 1023;    // Wr [256][1024]
            WrT[(size_t)n * F_MID + (k ^ ((n & 7) << 3))] = (f16)Wr[i];
        }
        return;
    }

    constexpr int BK = 64;
    constexpr int NW = TN / 64;
    constexpr int WM = BM / 64;
    constexpr int WN = NW / WM;
    constexpr int WTN = BN / WN;
    constexpr int FN = WTN / 16;
    constexpr int SMEM_STG = (2 * BM * BK + 2 * BN * BK) * 2;
    constexpr int LDC = BN + 8;
    constexpr int SMEM_EPI = BM * LDC * (C16 ? 2 : 4);
    constexpr int SMEM_SZ = SMEM_STG > SMEM_EPI ? SMEM_STG : SMEM_EPI;
    __shared__ __align__(16) char smem[SMEM_SZ];
    f16* As_ = (f16*)smem;                 // [2][BM*BK]
    f16* Bs_ = As_ + 2 * BM * BK;          // [2][BN*BK]

    const int tid = threadIdx.x, lane = tid & 63, wid = tid >> 6;
    const int l15 = lane & 15;
    const int wm = wid % WM, wn = wid / WM;
    const int col0 = blockIdx.y * BN;
    int row0 = blockIdx.x * (BM * M2);

    const int ar = tid >> 3;              // f32 A reg-staging (TN == BM*8)
    const int ac = (tid & 7) * 8;
    f32x4 av0 = {}, av1 = {};

    const int nkt = K / BK;

    auto stage_load = [&](int kt, int b) {
        const int k0 = kt * BK;
        if constexpr (A16) {
            const f16* A = (const f16*)Ag;
            #pragma unroll
            for (int i = wid; i < BM * BK / 512; i += NW) {
                int li = i * 512 + lane * 8;
                int r = li >> 6, c = li & 63;
                glds16(&A[(size_t)(row0 + r) * K + k0 + c], &As_[b * BM * BK + i * 512]);
            }
        } else {
            const float* A = (const float*)Ag;
            int gr = row0 + ar;
            if (gr < M) {
                av0 = __builtin_nontemporal_load((const f32x4*)&A[(size_t)gr * K + k0 + ac]);
                av1 = __builtin_nontemporal_load((const f32x4*)&A[(size_t)gr * K + k0 + ac + 4]);
            } else { av0 = (f32x4){}; av1 = (f32x4){}; }
        }
        #pragma unroll
        for (int i = wid; i < BN * BK / 512; i += NW) {
            int li = i * 512 + lane * 8;
            int r = li >> 6, c = li & 63;
            glds16(&BTg[(size_t)(col0 + r) * K + k0 + c], &Bs_[b * BN * BK + i * 512]);
        }
    };
    auto stage_write = [&](int b) {
        if constexpr (!A16) {
            f16x4 l = __builtin_convertvector(av0, f16x4);
            f16x4 h = __builtin_convertvector(av1, f16x4);
            f16x8 v = { l[0], l[1], l[2], l[3], h[0], h[1], h[2], h[3] };
            *(f16x8*)&As_[b * BM * BK + ar * 64 + (ac ^ ((ar & 7) << 3))] = v;
        }
    };

    #pragma unroll
    for (int m2 = 0; m2 < M2; ++m2) {
        row0 = blockIdx.x * (BM * M2) + m2 * BM;
        if (row0 >= M) break;

        f32x4 acc[4][FN] = {};
        int buf = 0;

        stage_load(0, 0);
        stage_write(0);
        __syncthreads();

        for (int kt = 0; kt < nkt; ++kt) {
            if (kt + 1 < nkt) stage_load(kt + 1, buf ^ 1);
            #pragma unroll
            for (int ks = 0; ks < 2; ++ks) {
                const int cc = ks * 32 + (lane >> 4) * 8;
                f16x8 af[4], bf[FN];
                #pragma unroll
                for (int m = 0; m < 4; ++m) {
                    int r = wm * 64 + m * 16 + l15;
                    af[m] = *(const f16x8*)&As_[buf * BM * BK + r * 64 + (cc ^ ((r & 7) << 3))];
                }
                #pragma unroll
                for (int n = 0; n < FN; ++n) {
                    int r = wn * WTN + n * 16 + l15;
                    bf[n] = *(const f16x8*)&Bs_[buf * BN * BK + r * 64 + (cc ^ ((r & 7) << 3))];
                }
                #pragma unroll
                for (int m = 0; m < 4; ++m)
                    #pragma unroll
                    for (int n = 0; n < FN; ++n)
                        acc[m][n] = __builtin_amdgcn_mfma_f32_16x16x32_f16(af[m], bf[n], acc[m][n], 0, 0, 0);
            }
            if (kt + 1 < nkt) stage_write(buf ^ 1);
            __syncthreads();
            buf ^= 1;
        }

        // ---- epilogue: acc -> LDS (stride LDC) -> contiguous vector stores ----
        // C/D frag mapping: col=lane&15, row=(lane>>4)*4+reg
        if constexpr (C16) {
            f16* CT = (f16*)smem;
            #pragma unroll
            for (int m = 0; m < 4; ++m)
                #pragma unroll
                for (int j = 0; j < 4; ++j) {
                    const int rl = wm * 64 + m * 16 + (lane >> 4) * 4 + j;
                    #pragma unroll
                    for (int n = 0; n < FN; ++n)
                        CT[rl * LDC + wn * WTN + n * 16 + l15] = (f16)acc[m][n][j];
                }
            __syncthreads();
            f16* C = (f16*)Cg;
            constexpr int NCH = BM * BN / 8;
            #pragma unroll
            for (int ci = tid; ci < NCH; ci += TN) {
                const int r = ci / (BN / 8), c = (ci % (BN / 8)) * 8;
                const int gr = row0 + r;
                if (gr < M) {
                    f16x8 v = *(const f16x8*)&CT[r * LDC + c];
                    *(f16x8*)&C[(size_t)gr * Ntot + col0 + c] = v;
                }
            }
        } else {
            float* CT = (float*)smem;
            #pragma unroll
            for (int m = 0; m < 4; ++m)
                #pragma unroll
                for (int j = 0; j < 4; ++j) {
                    const int rl = wm * 64 + m * 16 + (lane >> 4) * 4 + j;
                    #pragma unroll
                    for (int n = 0; n < FN; ++n)
                        CT[rl * LDC + wn * WTN + n * 16 + l15] = acc[m][n][j];
                }
            __syncthreads();
            float* C = (float*)Cg;
            constexpr int NCH = BM * BN / 4;
            #pragma unroll
            for (int ci = tid; ci < NCH; ci += TN) {
                const int r = ci / (BN / 4), c = (ci % (BN / 4)) * 4;
                const int gr = row0 + r;
                if (gr < M) {
                    f32x4 v = *(const f32x4*)&CT[r * LDC + c];
                    v += *(const f32x4*)&bias[col0 + c];
                    __builtin_nontemporal_store(v, (f32x4*)&C[(size_t)gr * Ntot + col0 + c]);
                }
            }
        }
        if (m2 + 1 < M2) __syncthreads();   // all CT reads done before next tile's staging
    }
}

// ---------------- aggregation (wave per row, unroll-4 gather, bucketed CSR, inline rsqrt) ----------------
// cnt = cursor[row] (edge count), dinv(i) = rsqrtf(cnt_i + 1) computed inline.
// SCALED_IN=1: rows carry dinv[src] -> acc = hin[row] + sum hin[s]
// SCALED_IN=0: unscaled             -> acc = di*hin[row] + sum rsqrt(deg_s+1)*hin[s]
// Then *= di.  POST: +b1, relu, dropout, *di.  SWZ: write col ^ ((row&7)<<3).
template<int POST, int SWZ, int SCALED_IN>
__global__ __launch_bounds__(256) void k_agg16(const f16* __restrict__ hin,
                                               f16* __restrict__ hout,
                                               const int* __restrict__ csr,
                                               const int* __restrict__ cnt_arr,
                                               const float* __restrict__ bias) {
    const int wid = threadIdx.x >> 6;
    const int lane = threadIdx.x & 63;
    const int row = blockIdx.x * 4 + wid;
    const int cnt = cnt_arr[row];
    const int ch = lane * 4;
    const float di = rsqrtf((float)(cnt + 1));
    const int* rowcsr = csr + (size_t)row * CSR_STRIDE;

    f32x4 acc = __builtin_convertvector(*(const f16x4*)&hin[(size_t)row * F_MID + ch], f32x4);
    if (!SCALED_IN) acc *= di;
    int k = 0;
    for (; k + 4 <= cnt; k += 4) {
        const int s0 = rowcsr[k], s1 = rowcsr[k + 1];
        const int s2 = rowcsr[k + 2], s3 = rowcsr[k + 3];
        f16x4 v0 = *(const f16x4*)&hin[(size_t)s0 * F_MID + ch];
        f16x4 v1 = *(const f16x4*)&hin[(size_t)s1 * F_MID + ch];
        f16x4 v2 = *(const f16x4*)&hin[(size_t)s2 * F_MID + ch];
        f16x4 v3 = *(const f16x4*)&hin[(size_t)s3 * F_MID + ch];
        if (SCALED_IN) {
            acc += __builtin_convertvector(v0, f32x4) + __builtin_convertvector(v1, f32x4)
                 + __builtin_convertvector(v2, f32x4) + __builtin_convertvector(v3, f32x4);
        } else {
            acc += rsqrtf((float)(cnt_arr[s0] + 1)) * __builtin_convertvector(v0, f32x4)
                 + rsqrtf((float)(cnt_arr[s1] + 1)) * __builtin_convertvector(v1, f32x4)
                 + rsqrtf((float)(cnt_arr[s2] + 1)) * __builtin_convertvector(v2, f32x4)
                 + rsqrtf((float)(cnt_arr[s3] + 1)) * __builtin_convertvector(v3, f32x4);
        }
    }
    for (; k < cnt; ++k) {
        const int s = rowcsr[k];
        f32x4 v = __builtin_convertvector(*(const f16x4*)&hin[(size_t)s * F_MID + ch], f32x4);
        acc += SCALED_IN ? v : rsqrtf((float)(cnt_arr[s] + 1)) * v;
    }
    acc *= di;

    if (POST) {
        const unsigned f0 = (unsigned)row * F_MID + (unsigned)ch;
        #pragma unroll
        for (int j = 0; j < 4; ++j) {
            float t = acc[j] + bias[ch + j];
            t = fmaxf(t, 0.0f);
            t = keep_mask(f0 + j) ? t * 2.0f : 0.0f;
            acc[j] = t * di;                 // pre-scale for next aggregation
        }
    }
    const int oc = SWZ ? (ch ^ ((row & 7) << 3)) : ch;
    *(f16x4*)&hout[(size_t)row * F_MID + oc] = __builtin_convertvector(acc, f16x4);
}

// ---------------- launch ----------------
extern "C" void kernel_launch(void* const* d_in, const int* in_sizes, int n_in,
                              void* d_out, int out_size, void* d_ws, size_t ws_size,
                              hipStream_t stream) {
    const float* x  = (const float*)d_in[0];
    const int*   ei = (const int*)d_in[1];
    const float* W1 = (const float*)d_in[2];
    const float* b1 = (const float*)d_in[3];
    const float* W2 = (const float*)d_in[4];
    const float* b2 = (const float*)d_in[5];
    float* out = (float*)d_out;

    // d_out doubles as fp16 scratch (dead before the final f32 overwrite):
    f16* h0 = (f16*)out;                               // [N,256] xW1, unscaled, linear
    f16* h1s = h0 + (size_t)N_NODES * F_MID;           // [N,256] post relu/dropout, dinv-scaled, linear

    // workspace (~40 MB)
    f16*   h2agg = (f16*)d_ws;                         // [N,256] agg2 out, row-swizzled (GEMM2 A)
    f16*   W1T   = h2agg + (size_t)(N_NODES + 64) * F_MID;  // [256][1024] swizzled (+pad: OOB-safe glds)
    f16*   W2T   = W1T + (size_t)F_MID * F_IN;         // [1024][256] swizzled
    int*   cursor= (int*)(W2T + (size_t)F_IN * F_MID); // [N] fill cursor == edge count (degree)
    int*   csr   = cursor + N_NODES;                   // [N*64] bucketed CSR
    int*   flag  = csr + (size_t)N_NODES * CSR_STRIDE; // [1] 1=int64, 0=int32

    // 1) prep: zero cursor, dtype detect, W1 -> W1T (swizzled)
    k_prep<<<256, 256, 0, stream>>>(W1, W1T, ei, cursor, flag);

    // 2) GEMM1 (+riders: bucketed-CSR fill, W2 -> W2T): h0 = x @ W1
    //    M2=2 persistent tiles -> mainx=391, +121 riders = 512 blocks = ONE scheduling round.
    {
        const int mainx = (N_NODES + 127) / 128;       // 391
        dim3 grid(mainx + 121, 1);                     // 512 exactly
        k_mfma<64, 256, 512, 2, false, true><<<grid, 512, 0, stream>>>(
            (const void*)x, W1T, (void*)h0, nullptr, N_NODES, F_MID, F_IN,
            mainx, ei, cursor, csr, flag, W2, W2T);
    }

    // 3) agg1: rsqrt-weighted gather; +b1, relu, dropout, pre-scale.  4) agg2: swizzled out.
    k_agg16<1, 0, 0><<<N_NODES / 4, 256, 0, stream>>>(h0, h1s, csr, cursor, b1);
    k_agg16<0, 1, 1><<<N_NODES / 4, 256, 0, stream>>>(h1s, h2agg, csr, cursor, nullptr);

    // 5) GEMM2: out = h2agg @ W2 + b2.  BM=64, BN=256, M2=1, grid (782,4)   [R22-best config]
    {
        const int mainx = (N_NODES + 63) / 64;
        dim3 grid(mainx, 4);
        k_mfma<64, 256, 512, 1, true, false><<<grid, 512, 0, stream>>>(
            (const void*)h2agg, W2T, (void*)out, b2, N_NODES, F_IN, F_MID,
            mainx, ei, cursor, csr, flag, W2, W2T);
    }
}